// Round 4
// baseline (789.542 us; speedup 1.0000x reference)
//
#include <hip/hip_runtime.h>
#include <hip/hip_bf16.h>
#include <stdint.h>

#define T_TOK 8192
#define H_DIM 1024
#define I_DIM 4096
#define NEXP  8
#define BM    128
#define FBK   64
#define RT_TILES 136
#define RMAX (RT_TILES * BM)   // 17408

typedef __attribute__((ext_vector_type(8))) short bf16x8;
typedef __attribute__((ext_vector_type(4))) float f32x4;

__device__ __forceinline__ unsigned short f2bf(float f) {
    unsigned int u = __float_as_uint(f);
    return (unsigned short)((u + 0x7FFFu + ((u >> 16) & 1u)) >> 16);  // RNE
}
__device__ __forceinline__ unsigned int pk2(float a, float b) {
    return (unsigned int)f2bf(a) | ((unsigned int)f2bf(b) << 16);
}
__device__ __forceinline__ void gl_lds16(const void* g, void* l) {
    __builtin_amdgcn_global_load_lds(
        (const __attribute__((address_space(1))) unsigned int*)g,
        (__attribute__((address_space(3))) unsigned int*)l, 16, 0, 0);
}

// ---------------- router: LDS-staged gw, coalesced x, NO atomics ----------------
__global__ __launch_bounds__(256) void router_k(const float* __restrict__ x,
                                                const float* __restrict__ gw,
                                                int2* __restrict__ ridx,
                                                float2* __restrict__ rw) {
    __shared__ float gwT[NEXP][H_DIM + 8];
    for (int i = threadIdx.x; i < H_DIM * NEXP; i += 256) {
        const int k = i >> 3, e = i & 7;
        gwT[e][k] = gw[i];
    }
    __syncthreads();
    const int wid = threadIdx.x >> 6, lane = threadIdx.x & 63;
    const int t = blockIdx.x * 4 + wid;
    const float4* xr = (const float4*)(x + (size_t)t * H_DIM);
    float acc[NEXP];
#pragma unroll
    for (int e = 0; e < NEXP; ++e) acc[e] = 0.f;
#pragma unroll
    for (int jj = 0; jj < 4; ++jj) {
        const float4 v = xr[jj * 64 + lane];
        const int kb = jj * 256 + lane * 4;
#pragma unroll
        for (int e = 0; e < NEXP; ++e) {
            const float4 g = *(const float4*)&gwT[e][kb];
            acc[e] += v.x * g.x + v.y * g.y + v.z * g.z + v.w * g.w;
        }
    }
#pragma unroll
    for (int e = 0; e < NEXP; ++e) {
#pragma unroll
        for (int off = 32; off > 0; off >>= 1) acc[e] += __shfl_xor(acc[e], off, 64);
    }
    if (lane == 0) {
        int i0 = 0; float l0 = acc[0];
#pragma unroll
        for (int e = 1; e < NEXP; ++e) if (acc[e] > l0) { l0 = acc[e]; i0 = e; }
        int i1 = -1; float l1 = -3.4e38f;
#pragma unroll
        for (int e = 0; e < NEXP; ++e) if (e != i0 && acc[e] > l1) { l1 = acc[e]; i1 = e; }
        float ee = __expf(l1 - l0);
        float w0 = 1.f / (1.f + ee);
        float w1 = 1.f - w0;
        ridx[t] = make_int2(i0, i1);
        rw[t]   = make_float2(w0, w1);
    }
}

// ---------------- plan: offs + deterministic ranks, single block, parallel reductions ----------------
__global__ __launch_bounds__(256) void plan_k(const int2* __restrict__ ridx,
                                              int* __restrict__ offs,
                                              int* __restrict__ rpos) {
    __shared__ int cnt[256][NEXP];      // 8 KB
    __shared__ int base_sh[256][NEXP];  // 8 KB
    __shared__ int tot_sh[NEXP];
    __shared__ int offs_sh[NEXP + 1];
    const int tid = threadIdx.x;
    const int t0 = tid * (T_TOK / 256); // 32 tokens per thread
    int c[NEXP];
#pragma unroll
    for (int e = 0; e < NEXP; ++e) c[e] = 0;
    for (int j = 0; j < T_TOK / 256; ++j) {
        const int2 ii = ridx[t0 + j];
#pragma unroll
        for (int e = 0; e < NEXP; ++e)
            c[e] += (ii.x == e ? 1 : 0) + (ii.y == e ? 1 : 0);
    }
#pragma unroll
    for (int e = 0; e < NEXP; ++e) cnt[tid][e] = c[e];
    __syncthreads();
    if (tid < NEXP) {
        int s = 0;
        for (int i = 0; i < 256; ++i) s += cnt[i][tid];
        tot_sh[tid] = s;
    }
    __syncthreads();
    if (tid == 0) {
        int o = 0;
#pragma unroll
        for (int e = 0; e < NEXP; ++e) {
            offs_sh[e] = o; offs[e] = o;
            o += (tot_sh[e] + BM - 1) & ~(BM - 1);
        }
        offs_sh[NEXP] = o; offs[NEXP] = o;
    }
    __syncthreads();
    if (tid < NEXP) {
        int run = offs_sh[tid];
        for (int i = 0; i < 256; ++i) {
            base_sh[i][tid] = run;
            run += cnt[i][tid];
        }
    }
    __syncthreads();
    int b[NEXP];
#pragma unroll
    for (int e = 0; e < NEXP; ++e) b[e] = base_sh[tid][e];
    for (int j = 0; j < T_TOK / 256; ++j) {
        const int2 ii = ridx[t0 + j];
        int r0 = 0, r1 = 0;
#pragma unroll
        for (int e = 0; e < NEXP; ++e) r0 += (ii.x == e ? b[e] : 0);
#pragma unroll
        for (int e = 0; e < NEXP; ++e) b[e] += (ii.x == e ? 1 : 0);
#pragma unroll
        for (int e = 0; e < NEXP; ++e) r1 += (ii.y == e ? b[e] : 0);
#pragma unroll
        for (int e = 0; e < NEXP; ++e) b[e] += (ii.y == e ? 1 : 0);
        rpos[2 * (t0 + j)]     = r0;
        rpos[2 * (t0 + j) + 1] = r1;
    }
}

// ========== merged: scatter_xg (blocks 0..2047) || w13t (blocks 2048..18431) ==========
// alias-clean: scatter writes xg/rwgt; w13t writes w13 (disjoint).
__global__ __launch_bounds__(256) void scatter_w13t_k(
        const float* __restrict__ x, const float* __restrict__ dom,
        const int2* __restrict__ ridx, const float2* __restrict__ rw,
        const int* __restrict__ rpos, float* __restrict__ rwgt,
        unsigned short* __restrict__ xg,
        const float* __restrict__ W1, const float* __restrict__ W3,
        unsigned short* __restrict__ w13) {
    __shared__ float st[64 * 65];
    if (blockIdx.x < 2048) {
        const int wid = threadIdx.x >> 6, lane = threadIdx.x & 63;
        const int t = blockIdx.x * 4 + wid;
        const int2 ii = ridx[t];
        const float2 ww = rw[t];
        const int r0 = rpos[2 * t], r1 = rpos[2 * t + 1];
        if (lane == 0) {
            rwgt[r0] = ww.x;
            rwgt[r1] = ww.y;
        }
        const float4* xr = (const float4*)(x + (size_t)t * H_DIM);
        float4 xv[4];
#pragma unroll
        for (int jj = 0; jj < 4; ++jj) xv[jj] = xr[jj * 64 + lane];
#pragma unroll
        for (int s = 0; s < 2; ++s) {
            const int e = s ? ii.y : ii.x;
            const int rr = s ? r1 : r0;
            const float4* dr = (const float4*)(dom + (size_t)e * H_DIM);
            unsigned short* op = xg + (size_t)rr * H_DIM;
#pragma unroll
            for (int jj = 0; jj < 4; ++jj) {
                const float4 b = dr[jj * 64 + lane];
                const int kb = jj * 256 + lane * 4;
                *(uint2*)(op + kb) = make_uint2(pk2(xv[jj].x + b.x, xv[jj].y + b.y),
                                                pk2(xv[jj].z + b.z, xv[jj].w + b.w));
            }
        }
    } else {
        const int idx = blockIdx.x - 2048;
        const int nt = idx & 63;
        const int kt = (idx >> 6) & 15;
        const int z  = idx >> 10;
        const int e = z >> 1, sel = z & 1;
        const float* src = (sel ? W3 : W1) + (size_t)e * H_DIM * I_DIM;
        const int t = threadIdx.x;
        const int kr = t >> 2, c0 = (t & 3) << 4;
        const float* sp = src + (size_t)(kt * 64 + kr) * I_DIM + nt * 64 + c0;
#pragma unroll
        for (int j = 0; j < 4; ++j) {
            float4 v = *(const float4*)(sp + j * 4);
            st[kr * 65 + c0 + j*4 + 0] = v.x; st[kr * 65 + c0 + j*4 + 1] = v.y;
            st[kr * 65 + c0 + j*4 + 2] = v.z; st[kr * 65 + c0 + j*4 + 3] = v.w;
        }
        __syncthreads();
        const int nl = t >> 2, k0 = (t & 3) << 4;
        const int n = nt * 64 + nl;
        const size_t drow = (size_t)e * 8192 + (size_t)((n >> 4) << 5) + (sel << 4) + (n & 15);
        unsigned short* dp = w13 + drow * H_DIM + kt * 64 + k0;
        unsigned int pk[8];
#pragma unroll
        for (int j = 0; j < 8; ++j)
            pk[j] = pk2(st[(k0 + 2*j) * 65 + nl], st[(k0 + 2*j + 1) * 65 + nl]);
        *(uint4*)dp = make_uint4(pk[0], pk[1], pk[2], pk[3]);
        *(uint4*)(dp + 8) = make_uint4(pk[4], pk[5], pk[6], pk[7]);
    }
}

// ========== merged: gemm1 || w2t, INTERLEAVED block IDs ==========
// w2t blocks are short memory-bound blocks (~24KB traffic each); interleaving them 1:1
// among the first 16384 IDs hides their 200MB under gemm1's spare BW (gemm uses 1.7 of
// 6.3 TB/s) instead of running as a sequential ~30us tail after the gemm blocks drain.
__global__ __launch_bounds__(256, 3) void gemm1_w2t_k(
        const unsigned short* __restrict__ xg,
        const unsigned short* __restrict__ w13,
        const int* __restrict__ offs,
        unsigned short* __restrict__ h,
        const float* __restrict__ W2,
        unsigned short* __restrict__ w2t) {
    __shared__ unsigned short smem[2 * BM * FBK];   // 32 KB, shared by both paths
    // ---- ID remap: bid<16384: even->gemm(bid>>1), odd->w2t(bid>>1); else gemm(8192+rest)
    const unsigned int bid = blockIdx.x;
    bool is_gemm;
    unsigned int sub;
    if (bid < 16384u) {
        is_gemm = ((bid & 1u) == 0u);
        sub = bid >> 1;                 // gemm 0..8191 or w2t 0..8191
    } else {
        is_gemm = true;
        sub = 8192u + (bid - 16384u);   // gemm 8192..8703
    }
    if (is_gemm) {
        unsigned short* As = smem;
        unsigned short* Bs = smem + BM * FBK;
        const int wg = (int)sub;
        const int bx = wg & 63, by = wg >> 6;
        const int r0 = by * BM;
        if (r0 >= offs[NEXP]) return;
        int e = 0;
#pragma unroll
        for (int i = 1; i < NEXP; ++i) if (offs[i] <= r0) e = i;

        const int t = threadIdx.x, wid = t >> 6, lane = t & 63;
        const int srow = wid * 8 + (lane >> 3);
        const int schunk = (lane & 7) ^ (lane >> 3);
        const unsigned short* Agp = xg + (size_t)(r0 + srow) * H_DIM + (schunk << 3);
        const unsigned short* Bgp = w13 + ((size_t)e * 8192 + bx * 128 + srow) * H_DIM + (schunk << 3);
        unsigned short* Al = As + wid * 512;
        unsigned short* Bl = Bs + wid * 512;

        const int fr = lane & 15, g = lane >> 4, h3 = lane & 7;
        const int wr = (wid >> 1) * 64, wc = (wid & 1) * 64;

        f32x4 acc[4][4];
#pragma unroll
        for (int m = 0; m < 4; ++m)
#pragma unroll
            for (int n = 0; n < 4; ++n) acc[m][n] = (f32x4){0.f, 0.f, 0.f, 0.f};

#pragma unroll 1
        for (int kt = 0; kt < H_DIM / FBK; ++kt) {
            __syncthreads();
#pragma unroll
            for (int i = 0; i < 4; ++i) {
                gl_lds16(Agp + kt * FBK + i * 32 * H_DIM, Al + i * 2048);
                gl_lds16(Bgp + kt * FBK + i * 32 * H_DIM, Bl + i * 2048);
            }
            __syncthreads();
#pragma unroll
            for (int s = 0; s < 2; ++s) {
                const int pc = (((s << 2) + g) ^ h3) << 3;
                bf16x8 a[4], b[4];
#pragma unroll
                for (int m = 0; m < 4; ++m)
                    a[m] = *(const bf16x8*)&As[(wr + m * 16 + fr) * FBK + pc];
#pragma unroll
                for (int n = 0; n < 4; ++n)
                    b[n] = *(const bf16x8*)&Bs[(wc + n * 16 + fr) * FBK + pc];
#pragma unroll
                for (int m = 0; m < 4; ++m)
#pragma unroll
                    for (int n = 0; n < 4; ++n)
                        acc[m][n] = __builtin_amdgcn_mfma_f32_16x16x32_bf16(a[m], b[n], acc[m][n], 0, 0, 0);
            }
        }
        const int colbase = bx * 64 + ((wc >> 5) << 4) + fr;
#pragma unroll
        for (int m = 0; m < 4; ++m) {
            const int rbase = r0 + wr + m * 16 + (g << 2);
#pragma unroll
            for (int q = 0; q < 4; ++q) {
                unsigned short* hp = h + (size_t)(rbase + q) * I_DIM;
#pragma unroll
                for (int p = 0; p < 2; ++p) {
                    float p1 = acc[m][2 * p][q], p3 = acc[m][2 * p + 1][q];
                    float sv = p1 / (1.f + __expf(-p1));
                    hp[colbase + p * 16] = f2bf(sv * p3);
                }
            }
        }
    } else {
        float* st = (float*)smem;                    // 16.6 KB of the 32 KB
        const int idx = (int)sub;
        const int nt = idx & 15;
        const int kt = (idx >> 4) & 63;
        const int e  = idx >> 10;
        const float* src = W2 + (size_t)e * I_DIM * H_DIM;
        const int t = threadIdx.x;
        const int kr = t >> 2, c0 = (t & 3) << 4;
        const float* sp = src + (size_t)(kt * 64 + kr) * H_DIM + nt * 64 + c0;
#pragma unroll
        for (int j = 0; j < 4; ++j) {
            float4 v = *(const float4*)(sp + j * 4);
            st[kr * 65 + c0 + j*4 + 0] = v.x; st[kr * 65 + c0 + j*4 + 1] = v.y;
            st[kr * 65 + c0 + j*4 + 2] = v.z; st[kr * 65 + c0 + j*4 + 3] = v.w;
        }
        __syncthreads();
        const int nl = t >> 2, k0 = (t & 3) << 4;
        unsigned short* dp = w2t + ((size_t)e * 1024 + nt * 64 + nl) * I_DIM + kt * 64 + k0;
        unsigned int pk[8];
#pragma unroll
        for (int j = 0; j < 8; ++j)
            pk[j] = pk2(st[(k0 + 2*j) * 65 + nl], st[(k0 + 2*j + 1) * 65 + nl]);
        *(uint4*)dp = make_uint4(pk[0], pk[1], pk[2], pk[3]);
        *(uint4*)(dp + 8) = make_uint4(pk[4], pk[5], pk[6], pk[7]);
    }
}

// ================= GEMM2: y = h @ W2, K-split x2 into partials (tail fix) =================
// blocks 0..1087 -> ks=0 (kt 0..31) write y0; blocks 1088..2175 -> ks=1 (kt 32..63) write y1.
__global__ __launch_bounds__(256, 3) void gemm2_ksplit_k(
        const unsigned short* __restrict__ hbuf,
        const unsigned short* __restrict__ w2t,
        const int* __restrict__ offs,
        float* __restrict__ y) {
    __shared__ unsigned short As[BM * FBK];
    __shared__ unsigned short Bs[BM * FBK];
    const int bid = blockIdx.x;               // 0..2175
    const int ks = (bid >= 1088) ? 1 : 0;
    const int sb = bid - ks * 1088;
    const int idx = sb >> 3;                  // 0..135 within XCD slot
    const int by = (sb & 7) * 17 + (idx >> 3);    // 136 = 8 * 17 by-tiles
    const int bx = idx & 7;
    const int r0 = by * BM;
    if (r0 >= offs[NEXP]) return;
    int e = 0;
#pragma unroll
    for (int i = 1; i < NEXP; ++i) if (offs[i] <= r0) e = i;

    const int t = threadIdx.x, wid = t >> 6, lane = t & 63;
    const int srow = wid * 8 + (lane >> 3);
    const int schunk = (lane & 7) ^ (lane >> 3);
    const unsigned short* Agp = hbuf + (size_t)(r0 + srow) * I_DIM + (schunk << 3);
    const unsigned short* Bgp = w2t + ((size_t)e * 1024 + bx * 128 + srow) * I_DIM + (schunk << 3);
    unsigned short* Al = &As[wid * 512];
    unsigned short* Bl = &Bs[wid * 512];

    const int fr = lane & 15, g = lane >> 4, h3 = lane & 7;
    const int wr = (wid >> 1) * 64, wc = (wid & 1) * 64;

    f32x4 acc[4][4];
#pragma unroll
    for (int m = 0; m < 4; ++m)
#pragma unroll
        for (int n = 0; n < 4; ++n) acc[m][n] = (f32x4){0.f, 0.f, 0.f, 0.f};

    const int kt0 = ks * 32;
#pragma unroll 1
    for (int kt = kt0; kt < kt0 + 32; ++kt) {
        __syncthreads();
#pragma unroll
        for (int i = 0; i < 4; ++i) {
            gl_lds16(Agp + kt * FBK + (size_t)i * 32 * I_DIM, Al + i * 2048);
            gl_lds16(Bgp + kt * FBK + (size_t)i * 32 * I_DIM, Bl + i * 2048);
        }
        __syncthreads();
#pragma unroll
        for (int s = 0; s < 2; ++s) {
            const int pcc = (((s << 2) + g) ^ h3) << 3;
            bf16x8 av[4], bv[4];
#pragma unroll
            for (int m = 0; m < 4; ++m)
                av[m] = *(const bf16x8*)&As[(wr + m * 16 + fr) * FBK + pcc];
#pragma unroll
            for (int n = 0; n < 4; ++n)
                bv[n] = *(const bf16x8*)&Bs[(wc + n * 16 + fr) * FBK + pcc];
#pragma unroll
            for (int m = 0; m < 4; ++m)
#pragma unroll
                for (int n = 0; n < 4; ++n)
                    acc[m][n] = __builtin_amdgcn_mfma_f32_16x16x32_bf16(av[m], bv[n], acc[m][n], 0, 0, 0);
        }
    }
    float* yo = y + (size_t)ks * ((size_t)RMAX * H_DIM);
#pragma unroll
    for (int m = 0; m < 4; ++m) {
#pragma unroll
        for (int q = 0; q < 4; ++q) {
            const int rr = r0 + wr + m * 16 + (g << 2) + q;
            float* yp = yo + (size_t)rr * H_DIM + bx * 128 + wc + fr;
#pragma unroll
            for (int n = 0; n < 4; ++n) yp[n * 16] = acc[m][n][q];
        }
    }
}

// ================= combine: out[t] = w0*(y0[r0]+y1[r0]) + w1*(y0[r1]+y1[r1]) =================
__global__ __launch_bounds__(256) void combine_k(const float* __restrict__ y,
                                                 const int* __restrict__ rpos,
                                                 const float* __restrict__ rwgt,
                                                 float* __restrict__ out) {
    const float* y1 = y + (size_t)RMAX * H_DIM;
    const int wid = threadIdx.x >> 6, lane = threadIdx.x & 63;
    const int t = blockIdx.x * 4 + wid;
    const int ra = rpos[2 * t], rb = rpos[2 * t + 1];
    const float wa = rwgt[ra], wb = rwgt[rb];
    const float4* pa0 = (const float4*)(y  + (size_t)ra * H_DIM);
    const float4* pa1 = (const float4*)(y1 + (size_t)ra * H_DIM);
    const float4* pb0 = (const float4*)(y  + (size_t)rb * H_DIM);
    const float4* pb1 = (const float4*)(y1 + (size_t)rb * H_DIM);
    float4* po = (float4*)(out + (size_t)t * H_DIM);
#pragma unroll
    for (int j = 0; j < 4; ++j) {
        const int i = lane + j * 64;
        float4 a0 = pa0[i], a1 = pa1[i], b0 = pb0[i], b1 = pb1[i];
        po[i] = make_float4(wa * (a0.x + a1.x) + wb * (b0.x + b1.x),
                            wa * (a0.y + a1.y) + wb * (b0.y + b1.y),
                            wa * (a0.z + a1.z) + wb * (b0.z + b1.z),
                            wa * (a0.w + a1.w) + wb * (b0.w + b1.w));
    }
}

// ---------------- workspace layout (w2t DEDICATED; total 379,851,264 <= proven 379,855,104) ----------------
#define WS_OFFS  0
#define WS_RIDX  256
#define WS_RW    (WS_RIDX + T_TOK * 8)            // 65792
#define WS_RWGT  (WS_RW + T_TOK * 8)              // 131328
#define WS_RPOS  (WS_RWGT + RMAX * 4)             // 200960
// header end 266496 -> align 266752
#define WS_W13   266752
#define WS_XG    (WS_W13 + (size_t)134217728)             // 134484480
#define WS_W2T   (WS_XG + (size_t)RMAX * H_DIM * 2)       // 170136064
#define WS_H     (WS_W2T + (size_t)67108864)              // 237244928
// y partials alias w13+xg (both dead after gemm1): 2 * 71,303,168 = 142,606,336 B
// ends at 266752 + 142,606,336 = 142,873,088 < WS_W2T (170,136,064)  -> clean
#define WS_Y     WS_W13

extern "C" void kernel_launch(void* const* d_in, const int* in_sizes, int n_in,
                              void* d_out, int out_size, void* d_ws, size_t ws_size,
                              hipStream_t stream) {
    (void)in_sizes; (void)n_in; (void)ws_size; (void)out_size;
    const float* x   = (const float*)d_in[0];
    const float* gw  = (const float*)d_in[1];
    const float* W1  = (const float*)d_in[2];
    const float* W2  = (const float*)d_in[3];
    const float* W3  = (const float*)d_in[4];
    const float* dom = (const float*)d_in[5];
    float* out = (float*)d_out;

    char* ws = (char*)d_ws;
    int*    offs   = (int*)(ws + WS_OFFS);
    int2*   ridx   = (int2*)(ws + WS_RIDX);
    float2* rw     = (float2*)(ws + WS_RW);
    float*  rwgt   = (float*)(ws + WS_RWGT);
    int*    rpos   = (int*)(ws + WS_RPOS);
    unsigned short* w13 = (unsigned short*)(ws + WS_W13);
    unsigned short* xg  = (unsigned short*)(ws + WS_XG);
    unsigned short* w2t = (unsigned short*)(ws + WS_W2T);  // dedicated (no alias)
    unsigned short* hb  = (unsigned short*)(ws + WS_H);
    float*          y   = (float*)(ws + WS_Y);             // 2 partials alias w13+xg (dead after gemm1)

    router_k<<<T_TOK / 4, 256, 0, stream>>>(x, gw, ridx, rw);
    plan_k<<<1, 256, 0, stream>>>(ridx, offs, rpos);
    scatter_w13t_k<<<2048 + 16384, 256, 0, stream>>>(x, dom, ridx, rw, rpos, rwgt, xg,
                                                     W1, W3, w13);
    gemm1_w2t_k<<<8704 + 8192, 256, 0, stream>>>(xg, w13, offs, hb, W2, w2t);
    gemm2_ksplit_k<<<2176, 256, 0, stream>>>(hb, w2t, offs, y);
    combine_k<<<T_TOK / 4, 256, 0, stream>>>(y, rpos, rwgt, out);
}

// Round 5
// 693.404 us; speedup vs baseline: 1.1386x; 1.1386x over previous
//
#include <hip/hip_runtime.h>
#include <hip/hip_bf16.h>
#include <stdint.h>

#define T_TOK 8192
#define H_DIM 1024
#define I_DIM 4096
#define NEXP  8
#define BM    128
#define FBK   64
#define RT_TILES 136
#define RMAX (RT_TILES * BM)   // 17408
#define NTILE_MAX 72

typedef __attribute__((ext_vector_type(8))) short bf16x8;
typedef __attribute__((ext_vector_type(4))) float f32x4;

__device__ __forceinline__ unsigned short f2bf(float f) {
    unsigned int u = __float_as_uint(f);
    return (unsigned short)((u + 0x7FFFu + ((u >> 16) & 1u)) >> 16);  // RNE
}
__device__ __forceinline__ unsigned int pk2(float a, float b) {
    return (unsigned int)f2bf(a) | ((unsigned int)f2bf(b) << 16);
}
__device__ __forceinline__ void gl_lds16(const void* g, void* l) {
    __builtin_amdgcn_global_load_lds(
        (const __attribute__((address_space(1))) unsigned int*)g,
        (__attribute__((address_space(3))) unsigned int*)l, 16, 0, 0);
}

// ---------------- router ----------------
__global__ __launch_bounds__(256) void router_k(const float* __restrict__ x,
                                                const float* __restrict__ gw,
                                                int2* __restrict__ ridx,
                                                float2* __restrict__ rw) {
    __shared__ float gwT[NEXP][H_DIM + 8];
    for (int i = threadIdx.x; i < H_DIM * NEXP; i += 256) {
        const int k = i >> 3, e = i & 7;
        gwT[e][k] = gw[i];
    }
    __syncthreads();
    const int wid = threadIdx.x >> 6, lane = threadIdx.x & 63;
    const int t = blockIdx.x * 4 + wid;
    const float4* xr = (const float4*)(x + (size_t)t * H_DIM);
    float acc[NEXP];
#pragma unroll
    for (int e = 0; e < NEXP; ++e) acc[e] = 0.f;
#pragma unroll
    for (int jj = 0; jj < 4; ++jj) {
        const float4 v = xr[jj * 64 + lane];
        const int kb = jj * 256 + lane * 4;
#pragma unroll
        for (int e = 0; e < NEXP; ++e) {
            const float4 g = *(const float4*)&gwT[e][kb];
            acc[e] += v.x * g.x + v.y * g.y + v.z * g.z + v.w * g.w;
        }
    }
#pragma unroll
    for (int e = 0; e < NEXP; ++e) {
#pragma unroll
        for (int off = 32; off > 0; off >>= 1) acc[e] += __shfl_xor(acc[e], off, 64);
    }
    if (lane == 0) {
        int i0 = 0; float l0 = acc[0];
#pragma unroll
        for (int e = 1; e < NEXP; ++e) if (acc[e] > l0) { l0 = acc[e]; i0 = e; }
        int i1 = -1; float l1 = -3.4e38f;
#pragma unroll
        for (int e = 0; e < NEXP; ++e) if (e != i0 && acc[e] > l1) { l1 = acc[e]; i1 = e; }
        float ee = __expf(l1 - l0);
        float w0 = 1.f / (1.f + ee);
        float w1 = 1.f - w0;
        ridx[t] = make_int2(i0, i1);
        rw[t]   = make_float2(w0, w1);
    }
}

// ---------------- plan: offs + ranks + 256-row tile table ----------------
__global__ __launch_bounds__(256) void plan_k(const int2* __restrict__ ridx,
                                              int* __restrict__ offs,
                                              int* __restrict__ rpos,
                                              int* __restrict__ tinfo) {
    __shared__ int cnt[256][NEXP];
    __shared__ int base_sh[256][NEXP];
    __shared__ int tot_sh[NEXP];
    __shared__ int offs_sh[NEXP + 1];
    const int tid = threadIdx.x;
    const int t0 = tid * (T_TOK / 256);
    int c[NEXP];
#pragma unroll
    for (int e = 0; e < NEXP; ++e) c[e] = 0;
    for (int j = 0; j < T_TOK / 256; ++j) {
        const int2 ii = ridx[t0 + j];
#pragma unroll
        for (int e = 0; e < NEXP; ++e)
            c[e] += (ii.x == e ? 1 : 0) + (ii.y == e ? 1 : 0);
    }
#pragma unroll
    for (int e = 0; e < NEXP; ++e) cnt[tid][e] = c[e];
    __syncthreads();
    if (tid < NEXP) {
        int s = 0;
        for (int i = 0; i < 256; ++i) s += cnt[i][tid];
        tot_sh[tid] = s;
    }
    __syncthreads();
    if (tid == 0) {
        int o = 0;
#pragma unroll
        for (int e = 0; e < NEXP; ++e) {
            offs_sh[e] = o; offs[e] = o;
            o += (tot_sh[e] + BM - 1) & ~(BM - 1);
        }
        offs_sh[NEXP] = o; offs[NEXP] = o;
        int ntl = 0;
        for (int e2 = 0; e2 < NEXP; ++e2) {
            const int oe = offs_sh[e2], on = offs_sh[e2 + 1];
            for (int r = oe; r < on; r += 256) {
                tinfo[1 + ntl] = r;
                tinfo[1 + NTILE_MAX + ntl] = e2;
                tinfo[1 + 2 * NTILE_MAX + ntl] = (r + 256 < on) ? r + 256 : on;
                ++ntl;
            }
        }
        tinfo[0] = ntl;
    }
    __syncthreads();
    if (tid < NEXP) {
        int run = offs_sh[tid];
        for (int i = 0; i < 256; ++i) {
            base_sh[i][tid] = run;
            run += cnt[i][tid];
        }
    }
    __syncthreads();
    int b[NEXP];
#pragma unroll
    for (int e = 0; e < NEXP; ++e) b[e] = base_sh[tid][e];
    for (int j = 0; j < T_TOK / 256; ++j) {
        const int2 ii = ridx[t0 + j];
        int r0 = 0, r1 = 0;
#pragma unroll
        for (int e = 0; e < NEXP; ++e) r0 += (ii.x == e ? b[e] : 0);
#pragma unroll
        for (int e = 0; e < NEXP; ++e) b[e] += (ii.x == e ? 1 : 0);
#pragma unroll
        for (int e = 0; e < NEXP; ++e) r1 += (ii.y == e ? b[e] : 0);
#pragma unroll
        for (int e = 0; e < NEXP; ++e) b[e] += (ii.y == e ? 1 : 0);
        rpos[2 * (t0 + j)]     = r0;
        rpos[2 * (t0 + j) + 1] = r1;
    }
}

// ========== merged: scatter_xg (0..2047) || w13t (2048..18431) ==========
__global__ __launch_bounds__(256) void scatter_w13t_k(
        const float* __restrict__ x, const float* __restrict__ dom,
        const int2* __restrict__ ridx, const float2* __restrict__ rw,
        const int* __restrict__ rpos, float* __restrict__ rwgt,
        unsigned short* __restrict__ xg,
        const float* __restrict__ W1, const float* __restrict__ W3,
        unsigned short* __restrict__ w13) {
    __shared__ float st[64 * 65];
    if (blockIdx.x < 2048) {
        const int wid = threadIdx.x >> 6, lane = threadIdx.x & 63;
        const int t = blockIdx.x * 4 + wid;
        const int2 ii = ridx[t];
        const float2 ww = rw[t];
        const int r0 = rpos[2 * t], r1 = rpos[2 * t + 1];
        if (lane == 0) {
            rwgt[r0] = ww.x;
            rwgt[r1] = ww.y;
        }
        const float4* xr = (const float4*)(x + (size_t)t * H_DIM);
        float4 xv[4];
#pragma unroll
        for (int jj = 0; jj < 4; ++jj) xv[jj] = xr[jj * 64 + lane];
#pragma unroll
        for (int s = 0; s < 2; ++s) {
            const int e = s ? ii.y : ii.x;
            const int rr = s ? r1 : r0;
            const float4* dr = (const float4*)(dom + (size_t)e * H_DIM);
            unsigned short* op = xg + (size_t)rr * H_DIM;
#pragma unroll
            for (int jj = 0; jj < 4; ++jj) {
                const float4 b = dr[jj * 64 + lane];
                const int kb = jj * 256 + lane * 4;
                *(uint2*)(op + kb) = make_uint2(pk2(xv[jj].x + b.x, xv[jj].y + b.y),
                                                pk2(xv[jj].z + b.z, xv[jj].w + b.w));
            }
        }
    } else {
        const int idx = blockIdx.x - 2048;
        const int nt = idx & 63;
        const int kt = (idx >> 6) & 15;
        const int z  = idx >> 10;
        const int e = z >> 1, sel = z & 1;
        const float* src = (sel ? W3 : W1) + (size_t)e * H_DIM * I_DIM;
        const int t = threadIdx.x;
        const int kr = t >> 2, c0 = (t & 3) << 4;
        const float* sp = src + (size_t)(kt * 64 + kr) * I_DIM + nt * 64 + c0;
#pragma unroll
        for (int j = 0; j < 4; ++j) {
            float4 v = *(const float4*)(sp + j * 4);
            st[kr * 65 + c0 + j*4 + 0] = v.x; st[kr * 65 + c0 + j*4 + 1] = v.y;
            st[kr * 65 + c0 + j*4 + 2] = v.z; st[kr * 65 + c0 + j*4 + 3] = v.w;
        }
        __syncthreads();
        const int nl = t >> 2, k0 = (t & 3) << 4;
        const int n = nt * 64 + nl;
        const size_t drow = (size_t)e * 8192 + (size_t)((n >> 4) << 5) + (sel << 4) + (n & 15);
        unsigned short* dp = w13 + drow * H_DIM + kt * 64 + k0;
        unsigned int pk[8];
#pragma unroll
        for (int j = 0; j < 8; ++j)
            pk[j] = pk2(st[(k0 + 2*j) * 65 + nl], st[(k0 + 2*j + 1) * 65 + nl]);
        *(uint4*)dp = make_uint4(pk[0], pk[1], pk[2], pk[3]);
        *(uint4*)(dp + 8) = make_uint4(pk[4], pk[5], pk[6], pk[7]);
    }
}

// ========== GEMM1 8-phase: 256x256, BK=64, 2x(A,B) bufs = 128 KiB, vmcnt(8)/K-tile ==========
// blocks 0..2303: gemm (by=bid>>5, bx=bid&31). blocks 2304..6399: w2t transpose (2 tiles/block).
#define SBAR __builtin_amdgcn_s_barrier()

#define STG(kt_, b_) do { const size_t ko = (size_t)(kt_) * 64; \
    gl_lds16(pA0 + ko, L + (b_) * 16384 + 0 * 4096 + dof); \
    gl_lds16(pA1 + ko, L + (b_) * 16384 + 1 * 4096 + dof); \
    gl_lds16(pA2 + ko, L + (b_) * 16384 + 2 * 4096 + dof); \
    gl_lds16(pA3 + ko, L + (b_) * 16384 + 3 * 4096 + dof); \
    gl_lds16(pB0 + ko, L + 32768 + (b_) * 16384 + 0 * 4096 + dof); \
    gl_lds16(pB1 + ko, L + 32768 + (b_) * 16384 + 1 * 4096 + dof); \
    gl_lds16(pB2 + ko, L + 32768 + (b_) * 16384 + 2 * 4096 + dof); \
    gl_lds16(pB3 + ko, L + 32768 + (b_) * 16384 + 3 * 4096 + dof); } while (0)

#define LDA(mh_, b_) do { _Pragma("unroll") for (int mi = 0; mi < 4; ++mi) { \
    a[mi][0] = *(const bf16x8*)(Ard + (b_) * 16384 + ((mh_) * 64 + mi * 16) * 64 + cb0); \
    a[mi][1] = *(const bf16x8*)(Ard + (b_) * 16384 + ((mh_) * 64 + mi * 16) * 64 + cb1); } } while (0)

#define LDB(nh_, dst, b_) do { _Pragma("unroll") for (int ni = 0; ni < 2; ++ni) { \
    dst[ni][0] = *(const bf16x8*)(Brd + (b_) * 16384 + ((nh_) * 2 + ni) * 1024 + cb0); \
    dst[ni][1] = *(const bf16x8*)(Brd + (b_) * 16384 + ((nh_) * 2 + ni) * 1024 + cb1); } } while (0)

#define MMQ(mh_, nh_, bb) do { __builtin_amdgcn_s_setprio(1); \
    _Pragma("unroll") for (int mi = 0; mi < 4; ++mi) \
    _Pragma("unroll") for (int ni = 0; ni < 2; ++ni) { \
        acc[(mh_) * 4 + mi][(nh_) * 2 + ni] = __builtin_amdgcn_mfma_f32_16x16x32_bf16( \
            a[mi][0], bb[ni][0], acc[(mh_) * 4 + mi][(nh_) * 2 + ni], 0, 0, 0); \
        acc[(mh_) * 4 + mi][(nh_) * 2 + ni] = __builtin_amdgcn_mfma_f32_16x16x32_bf16( \
            a[mi][1], bb[ni][1], acc[(mh_) * 4 + mi][(nh_) * 2 + ni], 0, 0, 0); } \
    __builtin_amdgcn_s_setprio(0); } while (0)

__global__ __launch_bounds__(512, 2) void gemm1_8ph_k(
        const unsigned short* __restrict__ xg,
        const unsigned short* __restrict__ w13,
        const int* __restrict__ tinfo,
        unsigned short* __restrict__ h,
        const float* __restrict__ W2,
        unsigned short* __restrict__ w2t) {
    __shared__ unsigned short L[65536];   // 128 KiB: A bufs [0,32768), B bufs [32768,65536)
    const int bid = blockIdx.x;
    if (bid < 2304) {
        const int by = bid >> 5, bx = bid & 31;
        if (by >= tinfo[0]) return;
        const int r0   = tinfo[1 + by];
        const int e    = tinfo[1 + NTILE_MAX + by];
        const int rend = tinfo[1 + 2 * NTILE_MAX + by];

        const int t = threadIdx.x;
        const int wid = t >> 6, lane = t & 63;
        const int wm = wid >> 2, wn = wid & 3;          // 2M x 4N
        const int fr = lane & 15, g = lane >> 4, h3 = fr & 7;

        // staging: linear LDS dest, source chunk pre-swizzled (chunk ^= row&7)
        const int srow = t >> 3;                         // 0..63 within 64-row chunk
        const int csrc = (t & 7) ^ (srow & 7);
        int ra0 = r0 + 0 * 64 + srow; if (ra0 > RMAX - 1) ra0 = RMAX - 1;
        int ra1 = r0 + 1 * 64 + srow; if (ra1 > RMAX - 1) ra1 = RMAX - 1;
        int ra2 = r0 + 2 * 64 + srow; if (ra2 > RMAX - 1) ra2 = RMAX - 1;
        int ra3 = r0 + 3 * 64 + srow; if (ra3 > RMAX - 1) ra3 = RMAX - 1;
        const unsigned short* pA0 = xg + (size_t)ra0 * H_DIM + csrc * 8;
        const unsigned short* pA1 = xg + (size_t)ra1 * H_DIM + csrc * 8;
        const unsigned short* pA2 = xg + (size_t)ra2 * H_DIM + csrc * 8;
        const unsigned short* pA3 = xg + (size_t)ra3 * H_DIM + csrc * 8;
        const size_t brow = (size_t)e * 8192 + (size_t)bx * 256 + srow;
        const unsigned short* pB0 = w13 + (brow + 0 * 64) * H_DIM + csrc * 8;
        const unsigned short* pB1 = w13 + (brow + 1 * 64) * H_DIM + csrc * 8;
        const unsigned short* pB2 = w13 + (brow + 2 * 64) * H_DIM + csrc * 8;
        const unsigned short* pB3 = w13 + (brow + 3 * 64) * H_DIM + csrc * 8;
        const int dof = wid * 512;                       // wave-uniform LDS base (shorts)

        // swizzled fragment reads (proven 3-bit XOR, BK=64: chunk = (ks*4+g)^h3)
        const int cb0 = ((0 + g) ^ h3) << 3;             // ks=0, shorts
        const int cb1 = ((4 + g) ^ h3) << 3;             // ks=1
        const unsigned short* Ard = L + (wm * 128 + fr) * 64;
        const unsigned short* Brd = L + 32768 + (wn * 64 + fr) * 64;

        f32x4 acc[8][4];
#pragma unroll
        for (int m = 0; m < 8; ++m)
#pragma unroll
            for (int n = 0; n < 4; ++n) acc[m][n] = (f32x4){0.f, 0.f, 0.f, 0.f};
        bf16x8 a[4][2], b0[2][2], b1[2][2];

        // prologue: tiles 0,1 -> bufs 0,1 (16 loads); vmcnt(8): tile0 done, tile1 in flight
        STG(0, 0); STG(1, 1);
        asm volatile("s_waitcnt vmcnt(8)" ::: "memory");
        SBAR;

#pragma unroll 1
        for (int kt = 0; kt < 16; ++kt) {
            const int bc = kt & 1;
            // q1: A-half0 + B-half0 reads (12)
            LDA(0, bc); LDB(0, b0, bc);
            SBAR; MMQ(0, 0, b0); SBAR;
            // q2: B-half1 reads (4)
            LDB(1, b1, bc);
            SBAR; MMQ(0, 1, b1); SBAR;
            // q3: A-half1 reads (8)
            LDA(1, bc);
            SBAR; MMQ(1, 1, b1); SBAR;
            // q4: stage tile kt+2 (burst of 8), counted vmcnt, MFMA overlaps the wait
            if (kt < 14) STG(kt + 2, bc);
            SBAR;
            MMQ(1, 0, b0);
            if (kt < 14)       asm volatile("s_waitcnt vmcnt(8)" ::: "memory");
            else if (kt == 14) asm volatile("s_waitcnt vmcnt(0)" ::: "memory");
            SBAR;
        }

        // epilogue: SwiGLU + masked bf16 store
#pragma unroll
        for (int mq = 0; mq < 8; ++mq) {
            const int rb = r0 + wm * 128 + mq * 16 + (g << 2);
#pragma unroll
            for (int q = 0; q < 4; ++q) {
                const int rr = rb + q;
                if (rr < rend) {
                    unsigned short* hp = h + (size_t)rr * I_DIM;
#pragma unroll
                    for (int p = 0; p < 2; ++p) {
                        float p1 = acc[mq][2 * p][q], p3 = acc[mq][2 * p + 1][q];
                        float sv = p1 / (1.f + __expf(-p1));
                        hp[((bx * 8 + wn * 2 + p) << 4) + fr] = f2bf(sv * p3);
                    }
                }
            }
        }
    } else {
        // w2t transpose: 2 tiles per 512-thread block
        float* st = (float*)L + (threadIdx.x >> 8) * (64 * 65);
        const int idx = (bid - 2304) * 2 + (threadIdx.x >> 8);
        const int tt = threadIdx.x & 255;
        const int nt = idx & 15;
        const int kt = (idx >> 4) & 63;
        const int e  = idx >> 10;
        const float* src = W2 + (size_t)e * I_DIM * H_DIM;
        const int kr = tt >> 2, c0 = (tt & 3) << 4;
        const float* sp = src + (size_t)(kt * 64 + kr) * H_DIM + nt * 64 + c0;
#pragma unroll
        for (int j = 0; j < 4; ++j) {
            float4 v = *(const float4*)(sp + j * 4);
            st[kr * 65 + c0 + j*4 + 0] = v.x; st[kr * 65 + c0 + j*4 + 1] = v.y;
            st[kr * 65 + c0 + j*4 + 2] = v.z; st[kr * 65 + c0 + j*4 + 3] = v.w;
        }
        __syncthreads();
        const int nl = tt >> 2, k0 = (tt & 3) << 4;
        unsigned short* dp = w2t + ((size_t)e * 1024 + nt * 64 + nl) * I_DIM + kt * 64 + k0;
        unsigned int pk[8];
#pragma unroll
        for (int j = 0; j < 8; ++j)
            pk[j] = pk2(st[(k0 + 2*j) * 65 + nl], st[(k0 + 2*j + 1) * 65 + nl]);
        *(uint4*)dp = make_uint4(pk[0], pk[1], pk[2], pk[3]);
        *(uint4*)(dp + 8) = make_uint4(pk[4], pk[5], pk[6], pk[7]);
    }
}

// ================= GEMM2: y = h @ W2, K-split x2 into partials =================
__global__ __launch_bounds__(256, 3) void gemm2_ksplit_k(
        const unsigned short* __restrict__ hbuf,
        const unsigned short* __restrict__ w2t,
        const int* __restrict__ offs,
        float* __restrict__ y) {
    __shared__ unsigned short As[BM * FBK];
    __shared__ unsigned short Bs[BM * FBK];
    const int bid = blockIdx.x;               // 0..2175
    const int ks = (bid >= 1088) ? 1 : 0;
    const int sb = bid - ks * 1088;
    const int idx = sb >> 3;
    const int by = (sb & 7) * 17 + (idx >> 3);
    const int bx = idx & 7;
    const int r0 = by * BM;
    if (r0 >= offs[NEXP]) return;
    int e = 0;
#pragma unroll
    for (int i = 1; i < NEXP; ++i) if (offs[i] <= r0) e = i;

    const int t = threadIdx.x, wid = t >> 6, lane = t & 63;
    const int srow = wid * 8 + (lane >> 3);
    const int schunk = (lane & 7) ^ (lane >> 3);
    const unsigned short* Agp = hbuf + (size_t)(r0 + srow) * I_DIM + (schunk << 3);
    const unsigned short* Bgp = w2t + ((size_t)e * 1024 + bx * 128 + srow) * I_DIM + (schunk << 3);
    unsigned short* Al = &As[wid * 512];
    unsigned short* Bl = &Bs[wid * 512];

    const int fr = lane & 15, g = lane >> 4, h3 = lane & 7;
    const int wr = (wid >> 1) * 64, wc = (wid & 1) * 64;

    f32x4 acc[4][4];
#pragma unroll
    for (int m = 0; m < 4; ++m)
#pragma unroll
        for (int n = 0; n < 4; ++n) acc[m][n] = (f32x4){0.f, 0.f, 0.f, 0.f};

    const int kt0 = ks * 32;
#pragma unroll 1
    for (int kt = kt0; kt < kt0 + 32; ++kt) {
        __syncthreads();
#pragma unroll
        for (int i = 0; i < 4; ++i) {
            gl_lds16(Agp + kt * FBK + (size_t)i * 32 * I_DIM, Al + i * 2048);
            gl_lds16(Bgp + kt * FBK + (size_t)i * 32 * I_DIM, Bl + i * 2048);
        }
        __syncthreads();
#pragma unroll
        for (int s = 0; s < 2; ++s) {
            const int pcc = (((s << 2) + g) ^ h3) << 3;
            bf16x8 av[4], bv[4];
#pragma unroll
            for (int m = 0; m < 4; ++m)
                av[m] = *(const bf16x8*)&As[(wr + m * 16 + fr) * FBK + pcc];
#pragma unroll
            for (int n = 0; n < 4; ++n)
                bv[n] = *(const bf16x8*)&Bs[(wc + n * 16 + fr) * FBK + pcc];
#pragma unroll
            for (int m = 0; m < 4; ++m)
#pragma unroll
                for (int n = 0; n < 4; ++n)
                    acc[m][n] = __builtin_amdgcn_mfma_f32_16x16x32_bf16(av[m], bv[n], acc[m][n], 0, 0, 0);
        }
    }
    float* yo = y + (size_t)ks * ((size_t)RMAX * H_DIM);
#pragma unroll
    for (int m = 0; m < 4; ++m) {
#pragma unroll
        for (int q = 0; q < 4; ++q) {
            const int rr = r0 + wr + m * 16 + (g << 2) + q;
            float* yp = yo + (size_t)rr * H_DIM + bx * 128 + wc + fr;
#pragma unroll
            for (int n = 0; n < 4; ++n) yp[n * 16] = acc[m][n][q];
        }
    }
}

// ================= combine =================
__global__ __launch_bounds__(256) void combine_k(const float* __restrict__ y,
                                                 const int* __restrict__ rpos,
                                                 const float* __restrict__ rwgt,
                                                 float* __restrict__ out) {
    const float* y1 = y + (size_t)RMAX * H_DIM;
    const int wid = threadIdx.x >> 6, lane = threadIdx.x & 63;
    const int t = blockIdx.x * 4 + wid;
    const int ra = rpos[2 * t], rb = rpos[2 * t + 1];
    const float wa = rwgt[ra], wb = rwgt[rb];
    const float4* pa0 = (const float4*)(y  + (size_t)ra * H_DIM);
    const float4* pa1 = (const float4*)(y1 + (size_t)ra * H_DIM);
    const float4* pb0 = (const float4*)(y  + (size_t)rb * H_DIM);
    const float4* pb1 = (const float4*)(y1 + (size_t)rb * H_DIM);
    float4* po = (float4*)(out + (size_t)t * H_DIM);
#pragma unroll
    for (int j = 0; j < 4; ++j) {
        const int i = lane + j * 64;
        float4 a0 = pa0[i], a1 = pa1[i], b0 = pb0[i], b1 = pb1[i];
        po[i] = make_float4(wa * (a0.x + a1.x) + wb * (b0.x + b1.x),
                            wa * (a0.y + a1.y) + wb * (b0.y + b1.y),
                            wa * (a0.z + a1.z) + wb * (b0.z + b1.z),
                            wa * (a0.w + a1.w) + wb * (b0.w + b1.w));
    }
}

// ---------------- workspace layout (total 379,852,032 <= proven 379,855,104) ----------------
#define WS_OFFS  0
#define WS_TILE  256
#define WS_RIDX  1280
#define WS_RW    (WS_RIDX + T_TOK * 8)            // 66816
#define WS_RWGT  (WS_RW + T_TOK * 8)              // 132352
#define WS_RPOS  (WS_RWGT + RMAX * 4)             // 201984
// header end 267520 (256-aligned)
#define WS_W13   267520
#define WS_XG    (WS_W13 + (size_t)134217728)             // 134485248
#define WS_W2T   (WS_XG + (size_t)RMAX * H_DIM * 2)       // 170136832
#define WS_H     (WS_W2T + (size_t)67108864)              // 237245696
// y partials alias w13+xg (dead after gemm1): ends 142,873,856 < WS_W2T -> clean
#define WS_Y     WS_W13

extern "C" void kernel_launch(void* const* d_in, const int* in_sizes, int n_in,
                              void* d_out, int out_size, void* d_ws, size_t ws_size,
                              hipStream_t stream) {
    (void)in_sizes; (void)n_in; (void)ws_size; (void)out_size;
    const float* x   = (const float*)d_in[0];
    const float* gw  = (const float*)d_in[1];
    const float* W1  = (const float*)d_in[2];
    const float* W2  = (const float*)d_in[3];
    const float* W3  = (const float*)d_in[4];
    const float* dom = (const float*)d_in[5];
    float* out = (float*)d_out;

    char* ws = (char*)d_ws;
    int*    offs   = (int*)(ws + WS_OFFS);
    int*    tinfo  = (int*)(ws + WS_TILE);
    int2*   ridx   = (int2*)(ws + WS_RIDX);
    float2* rw     = (float2*)(ws + WS_RW);
    float*  rwgt   = (float*)(ws + WS_RWGT);
    int*    rpos   = (int*)(ws + WS_RPOS);
    unsigned short* w13 = (unsigned short*)(ws + WS_W13);
    unsigned short* xg  = (unsigned short*)(ws + WS_XG);
    unsigned short* w2t = (unsigned short*)(ws + WS_W2T);
    unsigned short* hb  = (unsigned short*)(ws + WS_H);
    float*          y   = (float*)(ws + WS_Y);

    router_k<<<T_TOK / 4, 256, 0, stream>>>(x, gw, ridx, rw);
    plan_k<<<1, 256, 0, stream>>>(ridx, offs, rpos, tinfo);
    scatter_w13t_k<<<2048 + 16384, 256, 0, stream>>>(x, dom, ridx, rw, rpos, rwgt, xg,
                                                     W1, W3, w13);
    gemm1_8ph_k<<<2304 + 4096, 512, 0, stream>>>(xg, w13, tinfo, hb, W2, w2t);
    gemm2_ksplit_k<<<2176, 256, 0, stream>>>(hb, w2t, offs, y);
    combine_k<<<T_TOK / 4, 256, 0, stream>>>(y, rpos, rwgt, out);
}

// Round 7
// 604.879 us; speedup vs baseline: 1.3053x; 1.1464x over previous
//
#include <hip/hip_runtime.h>
#include <hip/hip_bf16.h>
#include <stdint.h>

#define T_TOK 8192
#define H_DIM 1024
#define I_DIM 4096
#define NEXP  8
#define BM    128
#define FBK   64
#define RT_TILES 136
#define RMAX (RT_TILES * BM)   // 17408

typedef __attribute__((ext_vector_type(8))) short bf16x8;
typedef __attribute__((ext_vector_type(4))) float f32x4;

__device__ __forceinline__ unsigned short f2bf(float f) {
    unsigned int u = __float_as_uint(f);
    return (unsigned short)((u + 0x7FFFu + ((u >> 16) & 1u)) >> 16);  // RNE
}
__device__ __forceinline__ unsigned int pk2(float a, float b) {
    return (unsigned int)f2bf(a) | ((unsigned int)f2bf(b) << 16);
}
__device__ __forceinline__ void gl_lds16(const void* g, void* l) {
    __builtin_amdgcn_global_load_lds(
        (const __attribute__((address_space(1))) unsigned int*)g,
        (__attribute__((address_space(3))) unsigned int*)l, 16, 0, 0);
}

// ---------------- router: LDS-staged gw, coalesced x, NO atomics ----------------
__global__ __launch_bounds__(256) void router_k(const float* __restrict__ x,
                                                const float* __restrict__ gw,
                                                int2* __restrict__ ridx,
                                                float2* __restrict__ rw) {
    __shared__ float gwT[NEXP][H_DIM + 8];
    for (int i = threadIdx.x; i < H_DIM * NEXP; i += 256) {
        const int k = i >> 3, e = i & 7;
        gwT[e][k] = gw[i];
    }
    __syncthreads();
    const int wid = threadIdx.x >> 6, lane = threadIdx.x & 63;
    const int t = blockIdx.x * 4 + wid;
    const float4* xr = (const float4*)(x + (size_t)t * H_DIM);
    float acc[NEXP];
#pragma unroll
    for (int e = 0; e < NEXP; ++e) acc[e] = 0.f;
#pragma unroll
    for (int jj = 0; jj < 4; ++jj) {
        const float4 v = xr[jj * 64 + lane];
        const int kb = jj * 256 + lane * 4;
#pragma unroll
        for (int e = 0; e < NEXP; ++e) {
            const float4 g = *(const float4*)&gwT[e][kb];
            acc[e] += v.x * g.x + v.y * g.y + v.z * g.z + v.w * g.w;
        }
    }
#pragma unroll
    for (int e = 0; e < NEXP; ++e) {
#pragma unroll
        for (int off = 32; off > 0; off >>= 1) acc[e] += __shfl_xor(acc[e], off, 64);
    }
    if (lane == 0) {
        int i0 = 0; float l0 = acc[0];
#pragma unroll
        for (int e = 1; e < NEXP; ++e) if (acc[e] > l0) { l0 = acc[e]; i0 = e; }
        int i1 = -1; float l1 = -3.4e38f;
#pragma unroll
        for (int e = 0; e < NEXP; ++e) if (e != i0 && acc[e] > l1) { l1 = acc[e]; i1 = e; }
        float ee = __expf(l1 - l0);
        float w0 = 1.f / (1.f + ee);
        float w1 = 1.f - w0;
        ridx[t] = make_int2(i0, i1);
        rw[t]   = make_float2(w0, w1);
    }
}

// ---------------- plan: offs + deterministic ranks, single block, parallel reductions ----------------
__global__ __launch_bounds__(256) void plan_k(const int2* __restrict__ ridx,
                                              int* __restrict__ offs,
                                              int* __restrict__ rpos) {
    __shared__ int cnt[256][NEXP];      // 8 KB
    __shared__ int base_sh[256][NEXP];  // 8 KB
    __shared__ int tot_sh[NEXP];
    __shared__ int offs_sh[NEXP + 1];
    const int tid = threadIdx.x;
    const int t0 = tid * (T_TOK / 256); // 32 tokens per thread
    int c[NEXP];
#pragma unroll
    for (int e = 0; e < NEXP; ++e) c[e] = 0;
    for (int j = 0; j < T_TOK / 256; ++j) {
        const int2 ii = ridx[t0 + j];
#pragma unroll
        for (int e = 0; e < NEXP; ++e)
            c[e] += (ii.x == e ? 1 : 0) + (ii.y == e ? 1 : 0);
    }
#pragma unroll
    for (int e = 0; e < NEXP; ++e) cnt[tid][e] = c[e];
    __syncthreads();
    if (tid < NEXP) {
        int s = 0;
        for (int i = 0; i < 256; ++i) s += cnt[i][tid];
        tot_sh[tid] = s;
    }
    __syncthreads();
    if (tid == 0) {
        int o = 0;
#pragma unroll
        for (int e = 0; e < NEXP; ++e) {
            offs_sh[e] = o; offs[e] = o;
            o += (tot_sh[e] + BM - 1) & ~(BM - 1);
        }
        offs_sh[NEXP] = o; offs[NEXP] = o;
    }
    __syncthreads();
    if (tid < NEXP) {
        int run = offs_sh[tid];
        for (int i = 0; i < 256; ++i) {
            base_sh[i][tid] = run;
            run += cnt[i][tid];
        }
    }
    __syncthreads();
    int b[NEXP];
#pragma unroll
    for (int e = 0; e < NEXP; ++e) b[e] = base_sh[tid][e];
    for (int j = 0; j < T_TOK / 256; ++j) {
        const int2 ii = ridx[t0 + j];
        int r0 = 0, r1 = 0;
#pragma unroll
        for (int e = 0; e < NEXP; ++e) r0 += (ii.x == e ? b[e] : 0);
#pragma unroll
        for (int e = 0; e < NEXP; ++e) b[e] += (ii.x == e ? 1 : 0);
#pragma unroll
        for (int e = 0; e < NEXP; ++e) r1 += (ii.y == e ? b[e] : 0);
#pragma unroll
        for (int e = 0; e < NEXP; ++e) b[e] += (ii.y == e ? 1 : 0);
        rpos[2 * (t0 + j)]     = r0;
        rpos[2 * (t0 + j) + 1] = r1;
    }
}

// ========== merged: scatter_xg (blocks 0..2047) || w13t (blocks 2048..18431) ==========
__global__ __launch_bounds__(256) void scatter_w13t_k(
        const float* __restrict__ x, const float* __restrict__ dom,
        const int2* __restrict__ ridx, const float2* __restrict__ rw,
        const int* __restrict__ rpos, float* __restrict__ rwgt,
        unsigned short* __restrict__ xg,
        const float* __restrict__ W1, const float* __restrict__ W3,
        unsigned short* __restrict__ w13) {
    __shared__ float st[64 * 65];
    if (blockIdx.x < 2048) {
        const int wid = threadIdx.x >> 6, lane = threadIdx.x & 63;
        const int t = blockIdx.x * 4 + wid;
        const int2 ii = ridx[t];
        const float2 ww = rw[t];
        const int r0 = rpos[2 * t], r1 = rpos[2 * t + 1];
        if (lane == 0) {
            rwgt[r0] = ww.x;
            rwgt[r1] = ww.y;
        }
        const float4* xr = (const float4*)(x + (size_t)t * H_DIM);
        float4 xv[4];
#pragma unroll
        for (int jj = 0; jj < 4; ++jj) xv[jj] = xr[jj * 64 + lane];
#pragma unroll
        for (int s = 0; s < 2; ++s) {
            const int e = s ? ii.y : ii.x;
            const int rr = s ? r1 : r0;
            const float4* dr = (const float4*)(dom + (size_t)e * H_DIM);
            unsigned short* op = xg + (size_t)rr * H_DIM;
#pragma unroll
            for (int jj = 0; jj < 4; ++jj) {
                const float4 b = dr[jj * 64 + lane];
                const int kb = jj * 256 + lane * 4;
                *(uint2*)(op + kb) = make_uint2(pk2(xv[jj].x + b.x, xv[jj].y + b.y),
                                                pk2(xv[jj].z + b.z, xv[jj].w + b.w));
            }
        }
    } else {
        const int idx = blockIdx.x - 2048;
        const int nt = idx & 63;
        const int kt = (idx >> 6) & 15;
        const int z  = idx >> 10;
        const int e = z >> 1, sel = z & 1;
        const float* src = (sel ? W3 : W1) + (size_t)e * H_DIM * I_DIM;
        const int t = threadIdx.x;
        const int kr = t >> 2, c0 = (t & 3) << 4;
        const float* sp = src + (size_t)(kt * 64 + kr) * I_DIM + nt * 64 + c0;
#pragma unroll
        for (int j = 0; j < 4; ++j) {
            float4 v = *(const float4*)(sp + j * 4);
            st[kr * 65 + c0 + j*4 + 0] = v.x; st[kr * 65 + c0 + j*4 + 1] = v.y;
            st[kr * 65 + c0 + j*4 + 2] = v.z; st[kr * 65 + c0 + j*4 + 3] = v.w;
        }
        __syncthreads();
        const int nl = t >> 2, k0 = (t & 3) << 4;
        const int n = nt * 64 + nl;
        const size_t drow = (size_t)e * 8192 + (size_t)((n >> 4) << 5) + (sel << 4) + (n & 15);
        unsigned short* dp = w13 + drow * H_DIM + kt * 64 + k0;
        unsigned int pk[8];
#pragma unroll
        for (int j = 0; j < 8; ++j)
            pk[j] = pk2(st[(k0 + 2*j) * 65 + nl], st[(k0 + 2*j + 1) * 65 + nl]);
        *(uint4*)dp = make_uint4(pk[0], pk[1], pk[2], pk[3]);
        *(uint4*)(dp + 8) = make_uint4(pk[4], pk[5], pk[6], pk[7]);
    }
}

// ========== merged: gemm1 (blocks 0..8703) || w2t (blocks 8704..16895, tail-fill) ==========
__global__ __launch_bounds__(256, 4) void gemm1_w2t_k(
        const unsigned short* __restrict__ xg,
        const unsigned short* __restrict__ w13,
        const int* __restrict__ offs,
        unsigned short* __restrict__ h,
        const float* __restrict__ W2,
        unsigned short* __restrict__ w2t) {
    __shared__ unsigned short smem[2 * BM * FBK];   // 32 KB, shared by both paths
    if (blockIdx.x < 8704) {
        unsigned short* As = smem;
        unsigned short* Bs = smem + BM * FBK;
        const int wg = blockIdx.x;
        const int bx = wg & 63, by = wg >> 6;
        const int r0 = by * BM;
        if (r0 >= offs[NEXP]) return;
        int e = 0;
#pragma unroll
        for (int i = 1; i < NEXP; ++i) if (offs[i] <= r0) e = i;

        const int t = threadIdx.x, wid = t >> 6, lane = t & 63;
        const int srow = wid * 8 + (lane >> 3);
        const int schunk = (lane & 7) ^ (lane >> 3);
        const unsigned short* Agp = xg + (size_t)(r0 + srow) * H_DIM + (schunk << 3);
        const unsigned short* Bgp = w13 + ((size_t)e * 8192 + bx * 128 + srow) * H_DIM + (schunk << 3);
        unsigned short* Al = As + wid * 512;
        unsigned short* Bl = Bs + wid * 512;

        const int fr = lane & 15, g = lane >> 4, h3 = lane & 7;
        const int wr = (wid >> 1) * 64, wc = (wid & 1) * 64;

        f32x4 acc[4][4];
#pragma unroll
        for (int m = 0; m < 4; ++m)
#pragma unroll
            for (int n = 0; n < 4; ++n) acc[m][n] = (f32x4){0.f, 0.f, 0.f, 0.f};

#pragma unroll 1
        for (int kt = 0; kt < H_DIM / FBK; ++kt) {
            __syncthreads();
#pragma unroll
            for (int i = 0; i < 4; ++i) {
                gl_lds16(Agp + kt * FBK + i * 32 * H_DIM, Al + i * 2048);
                gl_lds16(Bgp + kt * FBK + i * 32 * H_DIM, Bl + i * 2048);
            }
            __syncthreads();
#pragma unroll
            for (int s = 0; s < 2; ++s) {
                const int pc = (((s << 2) + g) ^ h3) << 3;
                bf16x8 a[4], b[4];
#pragma unroll
                for (int m = 0; m < 4; ++m)
                    a[m] = *(const bf16x8*)&As[(wr + m * 16 + fr) * FBK + pc];
#pragma unroll
                for (int n = 0; n < 4; ++n)
                    b[n] = *(const bf16x8*)&Bs[(wc + n * 16 + fr) * FBK + pc];
#pragma unroll
                for (int m = 0; m < 4; ++m)
#pragma unroll
                    for (int n = 0; n < 4; ++n)
                        acc[m][n] = __builtin_amdgcn_mfma_f32_16x16x32_bf16(a[m], b[n], acc[m][n], 0, 0, 0);
            }
        }
        const int colbase = bx * 64 + ((wc >> 5) << 4) + fr;
#pragma unroll
        for (int m = 0; m < 4; ++m) {
            const int rbase = r0 + wr + m * 16 + (g << 2);
#pragma unroll
            for (int q = 0; q < 4; ++q) {
                unsigned short* hp = h + (size_t)(rbase + q) * I_DIM;
#pragma unroll
                for (int p = 0; p < 2; ++p) {
                    float p1 = acc[m][2 * p][q], p3 = acc[m][2 * p + 1][q];
                    float sv = p1 / (1.f + __expf(-p1));
                    hp[colbase + p * 16] = f2bf(sv * p3);
                }
            }
        }
    } else {
        float* st = (float*)smem;                    // 16.6 KB of the 32 KB
        const int idx = blockIdx.x - 8704;
        const int nt = idx & 15;
        const int kt = (idx >> 4) & 63;
        const int e  = idx >> 10;
        const float* src = W2 + (size_t)e * I_DIM * H_DIM;
        const int t = threadIdx.x;
        const int kr = t >> 2, c0 = (t & 3) << 4;
        const float* sp = src + (size_t)(kt * 64 + kr) * H_DIM + nt * 64 + c0;
#pragma unroll
        for (int j = 0; j < 4; ++j) {
            float4 v = *(const float4*)(sp + j * 4);
            st[kr * 65 + c0 + j*4 + 0] = v.x; st[kr * 65 + c0 + j*4 + 1] = v.y;
            st[kr * 65 + c0 + j*4 + 2] = v.z; st[kr * 65 + c0 + j*4 + 3] = v.w;
        }
        __syncthreads();
        const int nl = t >> 2, k0 = (t & 3) << 4;
        unsigned short* dp = w2t + ((size_t)e * 1024 + nt * 64 + nl) * I_DIM + kt * 64 + k0;
        unsigned int pk[8];
#pragma unroll
        for (int j = 0; j < 8; ++j)
            pk[j] = pk2(st[(k0 + 2*j) * 65 + nl], st[(k0 + 2*j + 1) * 65 + nl]);
        *(uint4*)dp = make_uint4(pk[0], pk[1], pk[2], pk[3]);
        *(uint4*)(dp + 8) = make_uint4(pk[4], pk[5], pk[6], pk[7]);
    }
}

// ================= GEMM2: y = h @ W2, K-split x2 into partials (tail fix) =================
__global__ __launch_bounds__(256, 4) void gemm2_ksplit_k(
        const unsigned short* __restrict__ hbuf,
        const unsigned short* __restrict__ w2t,
        const int* __restrict__ offs,
        float* __restrict__ y) {
    __shared__ unsigned short As[BM * FBK];
    __shared__ unsigned short Bs[BM * FBK];
    const int bid = blockIdx.x;               // 0..2175
    const int ks = (bid >= 1088) ? 1 : 0;
    const int sb = bid - ks * 1088;
    const int idx = sb >> 3;                  // 0..135 within XCD slot
    const int by = (sb & 7) * 17 + (idx >> 3);    // 136 = 8 * 17 by-tiles
    const int bx = idx & 7;
    const int r0 = by * BM;
    if (r0 >= offs[NEXP]) return;
    int e = 0;
#pragma unroll
    for (int i = 1; i < NEXP; ++i) if (offs[i] <= r0) e = i;

    const int t = threadIdx.x, wid = t >> 6, lane = t & 63;
    const int srow = wid * 8 + (lane >> 3);
    const int schunk = (lane & 7) ^ (lane >> 3);
    const unsigned short* Agp = hbuf + (size_t)(r0 + srow) * I_DIM + (schunk << 3);
    const unsigned short* Bgp = w2t + ((size_t)e * 1024 + bx * 128 + srow) * I_DIM + (schunk << 3);
    unsigned short* Al = &As[wid * 512];
    unsigned short* Bl = &Bs[wid * 512];

    const int fr = lane & 15, g = lane >> 4, h3 = lane & 7;
    const int wr = (wid >> 1) * 64, wc = (wid & 1) * 64;

    f32x4 acc[4][4];
#pragma unroll
    for (int m = 0; m < 4; ++m)
#pragma unroll
        for (int n = 0; n < 4; ++n) acc[m][n] = (f32x4){0.f, 0.f, 0.f, 0.f};

    const int kt0 = ks * 32;
#pragma unroll 1
    for (int kt = kt0; kt < kt0 + 32; ++kt) {
        __syncthreads();
#pragma unroll
        for (int i = 0; i < 4; ++i) {
            gl_lds16(Agp + kt * FBK + (size_t)i * 32 * I_DIM, Al + i * 2048);
            gl_lds16(Bgp + kt * FBK + (size_t)i * 32 * I_DIM, Bl + i * 2048);
        }
        __syncthreads();
#pragma unroll
        for (int s = 0; s < 2; ++s) {
            const int pcc = (((s << 2) + g) ^ h3) << 3;
            bf16x8 av[4], bv[4];
#pragma unroll
            for (int m = 0; m < 4; ++m)
                av[m] = *(const bf16x8*)&As[(wr + m * 16 + fr) * FBK + pcc];
#pragma unroll
            for (int n = 0; n < 4; ++n)
                bv[n] = *(const bf16x8*)&Bs[(wc + n * 16 + fr) * FBK + pcc];
#pragma unroll
            for (int m = 0; m < 4; ++m)
#pragma unroll
                for (int n = 0; n < 4; ++n)
                    acc[m][n] = __builtin_amdgcn_mfma_f32_16x16x32_bf16(av[m], bv[n], acc[m][n], 0, 0, 0);
        }
    }
    float* yo = y + (size_t)ks * ((size_t)RMAX * H_DIM);
#pragma unroll
    for (int m = 0; m < 4; ++m) {
#pragma unroll
        for (int q = 0; q < 4; ++q) {
            const int rr = r0 + wr + m * 16 + (g << 2) + q;
            float* yp = yo + (size_t)rr * H_DIM + bx * 128 + wc + fr;
#pragma unroll
            for (int n = 0; n < 4; ++n) yp[n * 16] = acc[m][n][q];
        }
    }
}

// ================= combine: out[t] = w0*(y0[r0]+y1[r0]) + w1*(y0[r1]+y1[r1]) =================
__global__ __launch_bounds__(256) void combine_k(const float* __restrict__ y,
                                                 const int* __restrict__ rpos,
                                                 const float* __restrict__ rwgt,
                                                 float* __restrict__ out) {
    const float* y1 = y + (size_t)RMAX * H_DIM;
    const int wid = threadIdx.x >> 6, lane = threadIdx.x & 63;
    const int t = blockIdx.x * 4 + wid;
    const int ra = rpos[2 * t], rb = rpos[2 * t + 1];
    const float wa = rwgt[ra], wb = rwgt[rb];
    const f32x4* pa0 = (const f32x4*)(y  + (size_t)ra * H_DIM);
    const f32x4* pa1 = (const f32x4*)(y1 + (size_t)ra * H_DIM);
    const f32x4* pb0 = (const f32x4*)(y  + (size_t)rb * H_DIM);
    const f32x4* pb1 = (const f32x4*)(y1 + (size_t)rb * H_DIM);
    f32x4* po = (f32x4*)(out + (size_t)t * H_DIM);
#pragma unroll
    for (int j = 0; j < 4; ++j) {
        const int i = lane + j * 64;
        const f32x4 a0 = pa0[i], a1 = pa1[i], b0 = pb0[i], b1 = pb1[i];
        const f32x4 r = wa * (a0 + a1) + wb * (b0 + b1);
        __builtin_nontemporal_store(r, po + i);   // out never re-read: no write-allocate
    }
}

// ---------------- workspace layout (w2t DEDICATED; total 379,851,264 <= proven 379,855,104) ----------------
#define WS_OFFS  0
#define WS_RIDX  256
#define WS_RW    (WS_RIDX + T_TOK * 8)            // 65792
#define WS_RWGT  (WS_RW + T_TOK * 8)              // 131328
#define WS_RPOS  (WS_RWGT + RMAX * 4)             // 200960
// header end 266496 -> align 266752
#define WS_W13   266752
#define WS_XG    (WS_W13 + (size_t)134217728)             // 134484480
#define WS_W2T   (WS_XG + (size_t)RMAX * H_DIM * 2)       // 170136064
#define WS_H     (WS_W2T + (size_t)67108864)              // 237244928
// y partials alias w13+xg (both dead after gemm1): 2 * 71,303,168 = 142,606,336 B
// ends at 266752 + 142,606,336 = 142,873,088 < WS_W2T (170,136,064)  -> clean
#define WS_Y     WS_W13

extern "C" void kernel_launch(void* const* d_in, const int* in_sizes, int n_in,
                              void* d_out, int out_size, void* d_ws, size_t ws_size,
                              hipStream_t stream) {
    (void)in_sizes; (void)n_in; (void)ws_size; (void)out_size;
    const float* x   = (const float*)d_in[0];
    const float* gw  = (const float*)d_in[1];
    const float* W1  = (const float*)d_in[2];
    const float* W2  = (const float*)d_in[3];
    const float* W3  = (const float*)d_in[4];
    const float* dom = (const float*)d_in[5];
    float* out = (float*)d_out;

    char* ws = (char*)d_ws;
    int*    offs   = (int*)(ws + WS_OFFS);
    int2*   ridx   = (int2*)(ws + WS_RIDX);
    float2* rw     = (float2*)(ws + WS_RW);
    float*  rwgt   = (float*)(ws + WS_RWGT);
    int*    rpos   = (int*)(ws + WS_RPOS);
    unsigned short* w13 = (unsigned short*)(ws + WS_W13);
    unsigned short* xg  = (unsigned short*)(ws + WS_XG);
    unsigned short* w2t = (unsigned short*)(ws + WS_W2T);  // dedicated (no alias)
    unsigned short* hb  = (unsigned short*)(ws + WS_H);
    float*          y   = (float*)(ws + WS_Y);             // 2 partials alias w13+xg (dead after gemm1)

    router_k<<<T_TOK / 4, 256, 0, stream>>>(x, gw, ridx, rw);
    plan_k<<<1, 256, 0, stream>>>(ridx, offs, rpos);
    scatter_w13t_k<<<2048 + 16384, 256, 0, stream>>>(x, dom, ridx, rw, rpos, rwgt, xg,
                                                     W1, W3, w13);
    gemm1_w2t_k<<<8704 + 8192, 256, 0, stream>>>(xg, w13, offs, hb, W2, w2t);
    gemm2_ksplit_k<<<2176, 256, 0, stream>>>(hb, w2t, offs, y);
    combine_k<<<T_TOK / 4, 256, 0, stream>>>(y, rpos, rwgt, out);
}